// Round 11
// baseline (173.417 us; speedup 1.0000x reference)
//
#include <hip/hip_runtime.h>
#include <hip/hip_bf16.h>
#include <stdint.h>

// CausalMultiHeadAttention: B=4 S=2048 C=768 H=6 D=128
// cast(x,wT,Q-prescale) -> GEMM1(counted-vmcnt) -> V-transpose ->
// flash-attn(2-wave blocks, single-buf K/V split-phase pipeline, 4 blk/CU) -> GEMM2
#define SS 2048
#define CC 768
#define C3 2304
#define NITEMS (64 * 24)  // 32-row q-tiles x (b,h)
#define QSC 0.08838834764831845f  // 1/sqrt(128), folded into Q weights+bias

typedef float f32x4 __attribute__((ext_vector_type(4)));
typedef short s16x8 __attribute__((ext_vector_type(8)));

__device__ __forceinline__ unsigned short f2bf(float f) {
  union { float f; unsigned int u; } v; v.f = f;
  unsigned int r = (v.u + 0x7FFFu + ((v.u >> 16) & 1u)) >> 16;
  return (unsigned short)r;
}

__device__ __forceinline__ s16x8 ld8(const unsigned short* p) {
  return *reinterpret_cast<const s16x8*>(p);
}

__device__ __forceinline__ unsigned int cvt_pk_bf16(float lo, float hi) {
  unsigned int r;
  asm("v_cvt_pk_bf16_f32 %0, %1, %2" : "=v"(r) : "v"(lo), "v"(hi));
  return r;
}

// async global->LDS, 16B/lane. LDS dest = wave-uniform base + lane*16 (linear);
// per-lane global src carries the swizzle (rule #21: linear dest + inv-swz src).
__device__ __forceinline__ void gload_lds16(const unsigned short* g, unsigned short* l) {
  __builtin_amdgcn_global_load_lds(
      (const __attribute__((address_space(1))) void*)g,
      (__attribute__((address_space(3))) void*)l, 16, 0, 0);
}

__global__ __launch_bounds__(256) void cast_bf16_kernel(
    const float* __restrict__ src, unsigned short* __restrict__ dst, int n4) {
  int i = blockIdx.x * 256 + threadIdx.x;
  if (i < n4) {
    float4 v = reinterpret_cast<const float4*>(src)[i];
    ushort4 o;
    o.x = f2bf(v.x); o.y = f2bf(v.y); o.z = f2bf(v.z); o.w = f2bf(v.w);
    reinterpret_cast<ushort4*>(dst)[i] = o;
  }
}

// src [R][C] f32 -> dst [C][R] bf16; dst rows < nsc get scaled by QSC (Q fold)
__global__ __launch_bounds__(256) void transpose_cast_kernel(
    const float* __restrict__ src, unsigned short* __restrict__ dst, int R, int C,
    int nsc) {
  __shared__ float tile[32][33];
  int c0 = blockIdx.x * 32, r0 = blockIdx.y * 32;
  int tx = threadIdx.x & 31, ty = threadIdx.x >> 5;
  #pragma unroll
  for (int i = 0; i < 32; i += 8)
    tile[ty + i][tx] = src[(size_t)(r0 + ty + i) * C + c0 + tx];
  __syncthreads();
  #pragma unroll
  for (int i = 0; i < 32; i += 8) {
    int oc = c0 + ty + i;
    float v = tile[tx][ty + i];
    if (oc < nsc) v *= QSC;
    dst[(size_t)oc * R + r0 + tx] = f2bf(v);
  }
}

// V region of qkv [token][C3] -> vT [bh][d=128][n=S], 64x128 tiles via swizzled LDS
__global__ __launch_bounds__(256) void vtrans_kernel(
    const unsigned short* __restrict__ qkv, unsigned short* __restrict__ vT) {
  __shared__ unsigned short t[64 * 128];
  const int tid = threadIdx.x;
  const int n0 = blockIdx.x * 64;
  const int bh = blockIdx.y;
  const int b = bh / 6, h = bh % 6;
  #pragma unroll
  for (int it = 0; it < 4; ++it) {
    int c = it * 256 + tid;
    int n = c >> 4, slot = c & 15;
    s16x8 v = ld8(qkv + (size_t)(b * SS + n0 + n) * C3 + 2 * CC + h * 128 + slot * 8);
    int ss = slot ^ ((n >> 3) & 7);
    *reinterpret_cast<s16x8*>(&t[n * 128 + ss * 8]) = v;
  }
  __syncthreads();
  #pragma unroll
  for (int it = 0; it < 4; ++it) {
    int c = it * 256 + tid;
    int d = c >> 3, n8 = (c & 7) * 8;
    s16x8 o;
    #pragma unroll
    for (int j = 0; j < 8; ++j) {
      int n = n8 + j;
      int sl = (d >> 3) ^ ((n >> 3) & 7);
      o[j] = (short)t[n * 128 + sl * 8 + (d & 7)];
    }
    *reinterpret_cast<s16x8*>(&vT[((size_t)bh * 128 + d) * SS + n0 + n8]) = o;
  }
}

// C[m][n] = sum_k A[m][k]*Bt[n][k] + bias[n]. 128x128 tile, BK=32, 2 LDS bufs.
// r10-verified counted-vmcnt pipeline. bias cols < nsc scaled by QSC (Q fold).
template <int OUT_BF16>
__global__ __launch_bounds__(256) void gemm_lds_kernel(
    const unsigned short* __restrict__ A, const unsigned short* __restrict__ Bt,
    const float* __restrict__ bias, void* __restrict__ out, int M, int N, int K,
    int nsc) {
  __shared__ unsigned short lA[2][128 * 32];
  __shared__ unsigned short lB[2][128 * 32];
  const int tid = threadIdx.x, lane = tid & 63, w = tid >> 6;
  const int nbx = gridDim.x;
  int bid = blockIdx.y * nbx + blockIdx.x;
  const int cpx = (nbx * gridDim.y) >> 3;
  bid = (bid & 7) * cpx + (bid >> 3);
  const int m0 = (bid / nbx) * 128, n0 = (bid % nbx) * 128;
  const int lm = lane & 15, lg = lane >> 4;
  const int wm = (w >> 1) * 64, wn = (w & 1) * 64;
  const int sr = lane >> 2;                            // row-in-chunk 0..15
  const int ssl = ((lane & 3) ^ ((sr >> 1) & 3)) * 8;  // inv-swizzled k-slot
  int aOff[4], bOff[4];
  #pragma unroll
  for (int i = 0; i < 4; ++i) {
    int ra = wm + i * 16 + lm, rb = wn + i * 16 + lm;
    aOff[i] = ra * 32 + ((lg ^ ((ra >> 1) & 3)) * 8);
    bOff[i] = rb * 32 + ((lg ^ ((rb >> 1) & 3)) * 8);
  }
  f32x4 acc[4][4] = {};
  const int nt = K / 32;
  #define GSTAGE(tt, bb)                                                      \
    {                                                                         \
      const int k0_ = (tt) * 32;                                              \
      _Pragma("unroll")                                                       \
      for (int i_ = 0; i_ < 2; ++i_) {                                        \
        int c_ = w * 2 + i_;                                                  \
        int row_ = c_ * 16 + sr;                                              \
        gload_lds16(A + (size_t)(m0 + row_) * K + k0_ + ssl, &lA[bb][c_ * 512]); \
        gload_lds16(Bt + (size_t)(n0 + row_) * K + k0_ + ssl, &lB[bb][c_ * 512]); \
      }                                                                       \
    }
  GSTAGE(0, 0);
  #pragma unroll 1
  for (int t = 0; t < nt; ++t) {
    if (t + 1 < nt) {
      GSTAGE(t + 1, (t + 1) & 1);
      asm volatile("s_waitcnt vmcnt(4)" ::: "memory");  // tile t landed
    } else {
      asm volatile("s_waitcnt vmcnt(0)" ::: "memory");
    }
    __builtin_amdgcn_sched_barrier(0);
    __builtin_amdgcn_s_barrier();
    const int cu = t & 1;
    s16x8 af[4], bf[4];
    #pragma unroll
    for (int i = 0; i < 4; ++i) af[i] = ld8(&lA[cu][aOff[i]]);
    #pragma unroll
    for (int i = 0; i < 4; ++i) bf[i] = ld8(&lB[cu][bOff[i]]);
    __builtin_amdgcn_s_setprio(1);
    #pragma unroll
    for (int mi = 0; mi < 4; ++mi)
      #pragma unroll
      for (int ni = 0; ni < 4; ++ni)
        acc[mi][ni] = __builtin_amdgcn_mfma_f32_16x16x32_bf16(af[mi], bf[ni], acc[mi][ni], 0, 0, 0);
    __builtin_amdgcn_s_setprio(0);
    asm volatile("s_waitcnt lgkmcnt(0)" ::: "memory");
    __builtin_amdgcn_sched_barrier(0);
    __builtin_amdgcn_s_barrier();
  }
  #pragma unroll
  for (int mi = 0; mi < 4; ++mi) {
    #pragma unroll
    for (int ni = 0; ni < 4; ++ni) {
      const int row = m0 + wm + mi * 16 + lg * 4;
      const int col = n0 + wn + ni * 16 + lm;
      float bs = bias[col];
      if (col < nsc) bs *= QSC;
      #pragma unroll
      for (int r = 0; r < 4; ++r) {
        float v = acc[mi][ni][r] + bs;
        if (OUT_BF16)
          ((unsigned short*)out)[(size_t)(row + r) * N + col] = f2bf(v);
        else
          ((float*)out)[(size_t)(row + r) * N + col] = v;
      }
    }
  }
  #undef GSTAGE
}

// Flash attention, causal. 2-wave blocks (128 thr), item = (bh, 32-row q-tile),
// LPT queue. Single-buffered K and V, split-phase counted-vmcnt pipeline:
//   [vmcnt(8) bar QK fence bar, stage K(t+1)] softmax
//   [vmcnt(8|0) bar PV fence bar, stage V(t+1)]
// Every buffer overwrite is behind a fence+barrier that retired all readers.
// FIFO queue invariant at iter entry: [K(t)(8), V(t)(8)].
__global__ __launch_bounds__(128) void attn_kernel(
    const unsigned short* __restrict__ qkv,
    const unsigned short* __restrict__ vT,
    unsigned short* __restrict__ aout,
    int* __restrict__ ctr) {
  const int tid = threadIdx.x, lane = tid & 63, w = tid >> 6;  // w in {0,1}
  const int lm = lane & 15, lg = lane >> 4;
  __shared__ unsigned short kbuf[64 * 128];   // [kv-row][128], slot-swizzled
  __shared__ unsigned short vbuf[128 * 64];   // [d][64], slot-swizzled
  __shared__ unsigned int pb[2][16 * 36];     // per-wave P rows, u32 stride 36
  __shared__ int s_item;
  unsigned int* pr = &pb[w][lm * 36];
  const int klg4 = lane >> 4, ks16 = lane & 15;  // K staging: row-in-4, slot
  const int vlg8 = lane >> 3, vs8 = lane & 7;    // V staging: d-in-8, slot
  for (;;) {
    __syncthreads();
    if (tid == 0) s_item = atomicAdd(ctr, 1);
    __syncthreads();
    const int item = s_item;
    if (item >= NITEMS) return;
    const int qt = 63 - (item / 24);  // expensive q-tiles first (LPT)
    const int bh = item % 24;
    const int b = bh / 6, h = bh % 6;
    const int wq0 = qt * 32 + w * 16;
    const unsigned short* base = qkv + (size_t)b * SS * C3;
    const unsigned short* kg = base + CC + h * 128;
    const unsigned short* vg = vT + (size_t)bh * 128 * SS;
    s16x8 qf[4];
    {
      const unsigned short* qp = base + (size_t)(wq0 + lm) * C3 + h * 128 + lg * 8;
      #pragma unroll
      for (int ks = 0; ks < 4; ++ks) qf[ks] = ld8(qp + ks * 32);
    }
    // per-wave 8 chunks of 1KB each; wave w owns chunks w*8..w*8+7
    #define AK(tt)                                                            \
      {                                                                       \
        const int n1_ = (tt) * 64;                                            \
        _Pragma("unroll")                                                     \
        for (int i_ = 0; i_ < 8; ++i_) {                                      \
          int c_ = w * 8 + i_;                                                \
          int r_ = c_ * 4 + klg4;                                             \
          gload_lds16(kg + (size_t)(n1_ + r_) * C3 + ((ks16 ^ (r_ & 7)) * 8), \
                      &kbuf[c_ * 512]);                                       \
        }                                                                     \
      }
    #define AV(tt)                                                            \
      {                                                                       \
        const int n1_ = (tt) * 64;                                            \
        _Pragma("unroll")                                                     \
        for (int i_ = 0; i_ < 8; ++i_) {                                      \
          int c_ = w * 8 + i_;                                                \
          int d_ = c_ * 8 + vlg8;                                             \
          gload_lds16(vg + (size_t)d_ * SS + n1_ + ((vs8 ^ (d_ & 7)) * 8),    \
                      &vbuf[c_ * 512]);                                       \
        }                                                                     \
      }
    f32x4 oacc[8] = {};
    float m_run = -1e30f, l_run = 0.0f;
    const int nt = (qt >> 1) + 1;  // 64-wide kv tiles
    AK(0);
    AV(0);
    #pragma unroll 1
    for (int t = 0; t < nt; ++t) {
      // ---- QK phase: K(t) is oldest 8 of 16 outstanding ----
      asm volatile("s_waitcnt vmcnt(8)" ::: "memory");
      __builtin_amdgcn_sched_barrier(0);
      __builtin_amdgcn_s_barrier();   // K(t) visible to both waves
      const int n0 = t * 64;
      f32x4 sacc[4] = {};
      __builtin_amdgcn_s_setprio(1);
      #pragma unroll
      for (int nsub = 0; nsub < 4; ++nsub) {
        const int kr = (nsub * 16 + lm) * 128;
        #pragma unroll
        for (int ks = 0; ks < 4; ++ks) {
          s16x8 kf = ld8(&kbuf[kr + (((ks * 4 + lg) ^ (lm & 7)) * 8)]);
          sacc[nsub] = __builtin_amdgcn_mfma_f32_16x16x32_bf16(kf, qf[ks], sacc[nsub], 0, 0, 0);
        }
      }
      __builtin_amdgcn_s_setprio(0);
      asm volatile("s_waitcnt lgkmcnt(0)" ::: "memory");  // kbuf reads retired
      __builtin_amdgcn_sched_barrier(0);
      __builtin_amdgcn_s_barrier();   // release kbuf
      if (t + 1 < nt) AK(t + 1);      // overlaps softmax + PV
      // ---- softmax (Q pre-scaled by 1/sqrt(D)) ----
      const int qg = wq0 + lm;
      const bool full = (n0 + 63 <= wq0);
      float xs[4][4];
      float tmax = -1e30f;
      #pragma unroll
      for (int nsub = 0; nsub < 4; ++nsub) {
        #pragma unroll
        for (int r = 0; r < 4; ++r) {
          int n = n0 + nsub * 16 + lg * 4 + r;
          float x = sacc[nsub][r];
          if (!full && n > qg) x = -1e30f;
          xs[nsub][r] = x;
          tmax = fmaxf(tmax, x);
        }
      }
      tmax = fmaxf(tmax, __shfl_xor(tmax, 16));
      tmax = fmaxf(tmax, __shfl_xor(tmax, 32));
      const bool noresc = __all(tmax - m_run <= 8.0f);  // T13 defer-max
      const float m_new = noresc ? m_run : fmaxf(m_run, tmax);
      float psum = 0.0f;
      unsigned int pk_[4][2];
      #pragma unroll
      for (int nsub = 0; nsub < 4; ++nsub) {
        float p0 = __expf(xs[nsub][0] - m_new);
        float p1 = __expf(xs[nsub][1] - m_new);
        float p2 = __expf(xs[nsub][2] - m_new);
        float p3 = __expf(xs[nsub][3] - m_new);
        psum += (p0 + p1) + (p2 + p3);
        pk_[nsub][0] = cvt_pk_bf16(p0, p1);
        pk_[nsub][1] = cvt_pk_bf16(p2, p3);
      }
      psum += __shfl_xor(psum, 16);
      psum += __shfl_xor(psum, 32);
      if (!noresc) {
        const float resc = __expf(m_run - m_new);
        l_run *= resc;
        m_run = m_new;
        float rs[4];
        #pragma unroll
        for (int r = 0; r < 4; ++r) rs[r] = __shfl(resc, lg * 4 + r);
        #pragma unroll
        for (int dsub = 0; dsub < 8; ++dsub)
          #pragma unroll
          for (int r = 0; r < 4; ++r) oacc[dsub][r] *= rs[r];
      }
      l_run += psum;
      // stage P rows in per-wave LDS (uint2 = ds_write_b64)
      #pragma unroll
      for (int nsub = 0; nsub < 4; ++nsub) {
        uint2 pk2; pk2.x = pk_[nsub][0]; pk2.y = pk_[nsub][1];
        *reinterpret_cast<uint2*>(&pr[nsub * 8 + lg * 2]) = pk2;
      }
      // ---- PV phase: V(t) is oldest; K(t+1) may be in flight ----
      if (t + 1 < nt) {
        asm volatile("s_waitcnt vmcnt(8)" ::: "memory");  // V(t) landed
      } else {
        asm volatile("s_waitcnt vmcnt(0)" ::: "memory");
      }
      __builtin_amdgcn_sched_barrier(0);
      __builtin_amdgcn_s_barrier();   // V(t) visible to both waves
      __builtin_amdgcn_s_setprio(1);
      #pragma unroll
      for (int nch = 0; nch < 2; ++nch) {
        s16x8 pf = *reinterpret_cast<const s16x8*>(&pr[nch * 16 + lg * 4]);
        #pragma unroll
        for (int dsub = 0; dsub < 8; ++dsub) {
          const int vr = (dsub * 16 + lm) * 64;
          s16x8 vf = ld8(&vbuf[vr + (((nch * 4 + lg) ^ (lm & 7)) * 8)]);
          oacc[dsub] = __builtin_amdgcn_mfma_f32_16x16x32_bf16(pf, vf, oacc[dsub], 0, 0, 0);
        }
      }
      __builtin_amdgcn_s_setprio(0);
      asm volatile("s_waitcnt lgkmcnt(0)" ::: "memory");  // vbuf reads retired
      __builtin_amdgcn_sched_barrier(0);
      __builtin_amdgcn_s_barrier();   // release vbuf
      if (t + 1 < nt) AV(t + 1);      // overlaps next QK
    }
    #undef AK
    #undef AV
    float linv[4];
    #pragma unroll
    for (int r = 0; r < 4; ++r) linv[r] = 1.0f / __shfl(l_run, lg * 4 + r);
    #pragma unroll
    for (int dsub = 0; dsub < 8; ++dsub) {
      const int col = h * 128 + dsub * 16 + lm;
      #pragma unroll
      for (int r = 0; r < 4; ++r)
        aout[(size_t)(b * SS + wq0 + lg * 4 + r) * CC + col] =
            f2bf(oacc[dsub][r] * linv[r]);
    }
  }
}

extern "C" void kernel_launch(void* const* d_in, const int* in_sizes, int n_in,
                              void* d_out, int out_size, void* d_ws, size_t ws_size,
                              hipStream_t stream) {
  const float* x      = (const float*)d_in[0];
  const float* w_attn = (const float*)d_in[1];
  const float* b_attn = (const float*)d_in[2];
  const float* w_proj = (const float*)d_in[3];
  const float* b_proj = (const float*)d_in[4];
  float* out = (float*)d_out;

  const size_t M = 4 * (size_t)SS;  // 8192 tokens
  unsigned short* ws = (unsigned short*)d_ws;
  unsigned short* xb   = ws;                        // [8192,768] (dead after GEMM1)
  unsigned short* waT  = xb + M * CC;               // [2304,768]
  unsigned short* wpT  = waT + (size_t)C3 * CC;     // [768,768]
  unsigned short* qkv  = wpT + (size_t)CC * CC;     // [8192,2304]
  unsigned short* aout = qkv + M * C3;              // [8192,768]
  unsigned short* vT   = xb;                        // [24,128,2048] aliases dead xb
  int* ctr = (int*)(aout + M * CC);

  int n4 = (int)(M * CC / 4);
  cast_bf16_kernel<<<(n4 + 255) / 256, 256, 0, stream>>>(x, xb, n4);
  transpose_cast_kernel<<<dim3(C3 / 32, CC / 32), 256, 0, stream>>>(w_attn, waT, CC, C3, CC);
  transpose_cast_kernel<<<dim3(CC / 32, CC / 32), 256, 0, stream>>>(w_proj, wpT, CC, CC, 0);

  gemm_lds_kernel<1><<<dim3(C3 / 128, M / 128), 256, 0, stream>>>(
      xb, waT, b_attn, (void*)qkv, (int)M, C3, CC, CC);

  vtrans_kernel<<<dim3(SS / 64, 24), 256, 0, stream>>>(qkv, vT);

  hipMemsetAsync(ctr, 0, sizeof(int), stream);
  attn_kernel<<<1024, 128, 0, stream>>>(qkv, vT, aout, ctr);

  gemm_lds_kernel<0><<<dim3(CC / 128, M / 128), 256, 0, stream>>>(
      aout, wpT, b_proj, (void*)out, (int)M, CC, CC, 0);
}

// Round 12
// 169.918 us; speedup vs baseline: 1.0206x; 1.0206x over previous
//
#include <hip/hip_runtime.h>
#include <hip/hip_bf16.h>
#include <stdint.h>

// CausalMultiHeadAttention: B=4 S=2048 C=768 H=6 D=128
// cast(x,wT,Q-prescale) -> GEMM1(counted-vmcnt) -> V-transpose ->
// flash-attn(4-wave blocks, single-buf K/V split-phase, 3 blk/CU) -> GEMM2
#define SS 2048
#define CC 768
#define C3 2304
#define NITEMS 768  // (b,h) x 64-row q-tiles
#define QSC 0.08838834764831845f  // 1/sqrt(128), folded into Q weights+bias

typedef float f32x4 __attribute__((ext_vector_type(4)));
typedef short s16x8 __attribute__((ext_vector_type(8)));

__device__ __forceinline__ unsigned short f2bf(float f) {
  union { float f; unsigned int u; } v; v.f = f;
  unsigned int r = (v.u + 0x7FFFu + ((v.u >> 16) & 1u)) >> 16;
  return (unsigned short)r;
}

__device__ __forceinline__ s16x8 ld8(const unsigned short* p) {
  return *reinterpret_cast<const s16x8*>(p);
}

__device__ __forceinline__ unsigned int cvt_pk_bf16(float lo, float hi) {
  unsigned int r;
  asm("v_cvt_pk_bf16_f32 %0, %1, %2" : "=v"(r) : "v"(lo), "v"(hi));
  return r;
}

// async global->LDS, 16B/lane. LDS dest = wave-uniform base + lane*16 (linear);
// per-lane global src carries the swizzle (rule #21: linear dest + inv-swz src).
__device__ __forceinline__ void gload_lds16(const unsigned short* g, unsigned short* l) {
  __builtin_amdgcn_global_load_lds(
      (const __attribute__((address_space(1))) void*)g,
      (__attribute__((address_space(3))) void*)l, 16, 0, 0);
}

__global__ __launch_bounds__(256) void cast_bf16_kernel(
    const float* __restrict__ src, unsigned short* __restrict__ dst, int n4) {
  int i = blockIdx.x * 256 + threadIdx.x;
  if (i < n4) {
    float4 v = reinterpret_cast<const float4*>(src)[i];
    ushort4 o;
    o.x = f2bf(v.x); o.y = f2bf(v.y); o.z = f2bf(v.z); o.w = f2bf(v.w);
    reinterpret_cast<ushort4*>(dst)[i] = o;
  }
}

// src [R][C] f32 -> dst [C][R] bf16; dst rows < nsc get scaled by QSC (Q fold)
__global__ __launch_bounds__(256) void transpose_cast_kernel(
    const float* __restrict__ src, unsigned short* __restrict__ dst, int R, int C,
    int nsc) {
  __shared__ float tile[32][33];
  int c0 = blockIdx.x * 32, r0 = blockIdx.y * 32;
  int tx = threadIdx.x & 31, ty = threadIdx.x >> 5;
  #pragma unroll
  for (int i = 0; i < 32; i += 8)
    tile[ty + i][tx] = src[(size_t)(r0 + ty + i) * C + c0 + tx];
  __syncthreads();
  #pragma unroll
  for (int i = 0; i < 32; i += 8) {
    int oc = c0 + ty + i;
    float v = tile[tx][ty + i];
    if (oc < nsc) v *= QSC;
    dst[(size_t)oc * R + r0 + tx] = f2bf(v);
  }
}

// V region of qkv [token][C3] -> vT [bh][d=128][n=S], 64x128 tiles via swizzled LDS
__global__ __launch_bounds__(256) void vtrans_kernel(
    const unsigned short* __restrict__ qkv, unsigned short* __restrict__ vT) {
  __shared__ unsigned short t[64 * 128];
  const int tid = threadIdx.x;
  const int n0 = blockIdx.x * 64;
  const int bh = blockIdx.y;
  const int b = bh / 6, h = bh % 6;
  #pragma unroll
  for (int it = 0; it < 4; ++it) {
    int c = it * 256 + tid;
    int n = c >> 4, slot = c & 15;
    s16x8 v = ld8(qkv + (size_t)(b * SS + n0 + n) * C3 + 2 * CC + h * 128 + slot * 8);
    int ss = slot ^ ((n >> 3) & 7);
    *reinterpret_cast<s16x8*>(&t[n * 128 + ss * 8]) = v;
  }
  __syncthreads();
  #pragma unroll
  for (int it = 0; it < 4; ++it) {
    int c = it * 256 + tid;
    int d = c >> 3, n8 = (c & 7) * 8;
    s16x8 o;
    #pragma unroll
    for (int j = 0; j < 8; ++j) {
      int n = n8 + j;
      int sl = (d >> 3) ^ ((n >> 3) & 7);
      o[j] = (short)t[n * 128 + sl * 8 + (d & 7)];
    }
    *reinterpret_cast<s16x8*>(&vT[((size_t)bh * 128 + d) * SS + n0 + n8]) = o;
  }
}

// C[m][n] = sum_k A[m][k]*Bt[n][k] + bias[n]. 128x128 tile, BK=32, 2 LDS bufs.
// r10-verified counted-vmcnt pipeline. bias cols < nsc scaled by QSC (Q fold).
template <int OUT_BF16>
__global__ __launch_bounds__(256) void gemm_lds_kernel(
    const unsigned short* __restrict__ A, const unsigned short* __restrict__ Bt,
    const float* __restrict__ bias, void* __restrict__ out, int M, int N, int K,
    int nsc) {
  __shared__ unsigned short lA[2][128 * 32];
  __shared__ unsigned short lB[2][128 * 32];
  const int tid = threadIdx.x, lane = tid & 63, w = tid >> 6;
  const int nbx = gridDim.x;
  int bid = blockIdx.y * nbx + blockIdx.x;
  const int cpx = (nbx * gridDim.y) >> 3;
  bid = (bid & 7) * cpx + (bid >> 3);
  const int m0 = (bid / nbx) * 128, n0 = (bid % nbx) * 128;
  const int lm = lane & 15, lg = lane >> 4;
  const int wm = (w >> 1) * 64, wn = (w & 1) * 64;
  const int sr = lane >> 2;                            // row-in-chunk 0..15
  const int ssl = ((lane & 3) ^ ((sr >> 1) & 3)) * 8;  // inv-swizzled k-slot
  int aOff[4], bOff[4];
  #pragma unroll
  for (int i = 0; i < 4; ++i) {
    int ra = wm + i * 16 + lm, rb = wn + i * 16 + lm;
    aOff[i] = ra * 32 + ((lg ^ ((ra >> 1) & 3)) * 8);
    bOff[i] = rb * 32 + ((lg ^ ((rb >> 1) & 3)) * 8);
  }
  f32x4 acc[4][4] = {};
  const int nt = K / 32;
  #define GSTAGE(tt, bb)                                                      \
    {                                                                         \
      const int k0_ = (tt) * 32;                                              \
      _Pragma("unroll")                                                       \
      for (int i_ = 0; i_ < 2; ++i_) {                                        \
        int c_ = w * 2 + i_;                                                  \
        int row_ = c_ * 16 + sr;                                              \
        gload_lds16(A + (size_t)(m0 + row_) * K + k0_ + ssl, &lA[bb][c_ * 512]); \
        gload_lds16(Bt + (size_t)(n0 + row_) * K + k0_ + ssl, &lB[bb][c_ * 512]); \
      }                                                                       \
    }
  GSTAGE(0, 0);
  #pragma unroll 1
  for (int t = 0; t < nt; ++t) {
    if (t + 1 < nt) {
      GSTAGE(t + 1, (t + 1) & 1);
      asm volatile("s_waitcnt vmcnt(4)" ::: "memory");  // tile t landed
    } else {
      asm volatile("s_waitcnt vmcnt(0)" ::: "memory");
    }
    __builtin_amdgcn_sched_barrier(0);
    __builtin_amdgcn_s_barrier();
    const int cu = t & 1;
    s16x8 af[4], bf[4];
    #pragma unroll
    for (int i = 0; i < 4; ++i) af[i] = ld8(&lA[cu][aOff[i]]);
    #pragma unroll
    for (int i = 0; i < 4; ++i) bf[i] = ld8(&lB[cu][bOff[i]]);
    __builtin_amdgcn_s_setprio(1);
    #pragma unroll
    for (int mi = 0; mi < 4; ++mi)
      #pragma unroll
      for (int ni = 0; ni < 4; ++ni)
        acc[mi][ni] = __builtin_amdgcn_mfma_f32_16x16x32_bf16(af[mi], bf[ni], acc[mi][ni], 0, 0, 0);
    __builtin_amdgcn_s_setprio(0);
    asm volatile("s_waitcnt lgkmcnt(0)" ::: "memory");
    __builtin_amdgcn_sched_barrier(0);
    __builtin_amdgcn_s_barrier();
  }
  #pragma unroll
  for (int mi = 0; mi < 4; ++mi) {
    #pragma unroll
    for (int ni = 0; ni < 4; ++ni) {
      const int row = m0 + wm + mi * 16 + lg * 4;
      const int col = n0 + wn + ni * 16 + lm;
      float bs = bias[col];
      if (col < nsc) bs *= QSC;
      #pragma unroll
      for (int r = 0; r < 4; ++r) {
        float v = acc[mi][ni][r] + bs;
        if (OUT_BF16)
          ((unsigned short*)out)[(size_t)(row + r) * N + col] = f2bf(v);
        else
          ((float*)out)[(size_t)(row + r) * N + col] = v;
      }
    }
  }
  #undef GSTAGE
}

// Flash attention, causal. 4-wave blocks; item = (bh, 64-row q-tile), static
// balanced mapping (CU triplets {j, 767-j, 256+j} sum to ~const work).
// Single-buffered K and V, split-phase counted-vmcnt pipeline (4 loads/phase):
//   [vmcnt(4) bar QK fence bar, stage K(t+1)] softmax
//   [vmcnt(4|0) bar PV fence bar, stage V(t+1)]
// FIFO invariant at QK(t): [K(t)x4, V(t)x4]; at PV(t): [V(t)x4, K(t+1)x4].
__global__ __launch_bounds__(256) void attn_kernel(
    const unsigned short* __restrict__ qkv,
    const unsigned short* __restrict__ vT,
    unsigned short* __restrict__ aout,
    int* __restrict__ ctr) {
  const int tid = threadIdx.x, lane = tid & 63, w = tid >> 6;
  const int lm = lane & 15, lg = lane >> 4;
  __shared__ unsigned short kbuf[64 * 128];   // [kv-row][128], slot-swizzled
  __shared__ unsigned short vbuf[128 * 64];   // [d][64], slot-swizzled
  __shared__ unsigned int pb[4][16 * 36];     // per-wave P rows, u32 stride 36
  __shared__ int s_item;
  unsigned int* pr = &pb[w][lm * 36];
  const int klg4 = lane >> 4, ks16 = lane & 15;  // K staging: row-in-4, slot
  const int vlg8 = lane >> 3, vs8 = lane & 7;    // V staging: d-in-8, slot
  for (;;) {
    __syncthreads();
    if (tid == 0) s_item = atomicAdd(ctr, 1);
    __syncthreads();
    const int item = s_item;
    if (item >= NITEMS) return;
    // balanced triplet mapping: blocks c, c+256, c+512 (one CU) get ranks
    // j, 767-j, 256+j -> per-CU tile totals ~const (42.7..53.3)
    const int j = item & 255, g = item >> 8;
    const int r = (g == 0) ? j : ((g == 1) ? 767 - j : 256 + j);
    const int qt = 31 - (r / 24);
    const int bh = r % 24;
    const int b = bh / 6, h = bh % 6;
    const int wq0 = qt * 64 + w * 16;
    const unsigned short* base = qkv + (size_t)b * SS * C3;
    const unsigned short* kg = base + CC + h * 128;
    const unsigned short* vg = vT + (size_t)bh * 128 * SS;
    s16x8 qf[4];
    {
      const unsigned short* qp = base + (size_t)(wq0 + lm) * C3 + h * 128 + lg * 8;
      #pragma unroll
      for (int ks = 0; ks < 4; ++ks) qf[ks] = ld8(qp + ks * 32);
    }
    // 16 chunks of 1KB per tile; wave w owns chunks w*4..w*4+3 (4 loads/phase)
    #define AK(tt)                                                            \
      {                                                                       \
        const int n1_ = (tt) * 64;                                            \
        _Pragma("unroll")                                                     \
        for (int i_ = 0; i_ < 4; ++i_) {                                      \
          int c_ = w * 4 + i_;                                                \
          int r_ = c_ * 4 + klg4;                                             \
          gload_lds16(kg + (size_t)(n1_ + r_) * C3 + ((ks16 ^ (r_ & 7)) * 8), \
                      &kbuf[c_ * 512]);                                       \
        }                                                                     \
      }
    #define AV(tt)                                                            \
      {                                                                       \
        const int n1_ = (tt) * 64;                                            \
        _Pragma("unroll")                                                     \
        for (int i_ = 0; i_ < 4; ++i_) {                                      \
          int c_ = w * 4 + i_;                                                \
          int d_ = c_ * 8 + vlg8;                                             \
          gload_lds16(vg + (size_t)d_ * SS + n1_ + ((vs8 ^ (d_ & 7)) * 8),    \
                      &vbuf[c_ * 512]);                                       \
        }                                                                     \
      }
    f32x4 oacc[8] = {};
    float m_run = -1e30f, l_run = 0.0f;
    const int nt = qt + 1;  // 64-wide kv tiles
    AK(0);
    AV(0);
    #pragma unroll 1
    for (int t = 0; t < nt; ++t) {
      const int n0 = t * 64;
      const bool active = (n0 <= wq0 + 15);
      // ---- QK phase: K(t) is oldest 4 of 8 outstanding ----
      if (t + 1 < nt) {
        asm volatile("s_waitcnt vmcnt(4)" ::: "memory");  // K(t) landed
      } else {
        asm volatile("s_waitcnt vmcnt(4)" ::: "memory");  // [K(t),V(t)] only
      }
      __builtin_amdgcn_sched_barrier(0);
      __builtin_amdgcn_s_barrier();   // K(t) visible to all waves
      f32x4 sacc[4] = {};
      if (active) {
        __builtin_amdgcn_s_setprio(1);
        #pragma unroll
        for (int nsub = 0; nsub < 4; ++nsub) {
          const int kr = (nsub * 16 + lm) * 128;
          #pragma unroll
          for (int ks = 0; ks < 4; ++ks) {
            s16x8 kf = ld8(&kbuf[kr + (((ks * 4 + lg) ^ (lm & 7)) * 8)]);
            sacc[nsub] = __builtin_amdgcn_mfma_f32_16x16x32_bf16(kf, qf[ks], sacc[nsub], 0, 0, 0);
          }
        }
        __builtin_amdgcn_s_setprio(0);
      }
      asm volatile("s_waitcnt lgkmcnt(0)" ::: "memory");  // kbuf reads retired
      __builtin_amdgcn_sched_barrier(0);
      __builtin_amdgcn_s_barrier();   // release kbuf
      if (t + 1 < nt) AK(t + 1);      // overlaps softmax + PV
      // ---- softmax (Q pre-scaled by 1/sqrt(D)) ----
      if (active) {
        const int qg = wq0 + lm;
        const bool full = (n0 + 63 <= wq0);
        float xs[4][4];
        float tmax = -1e30f;
        #pragma unroll
        for (int nsub = 0; nsub < 4; ++nsub) {
          #pragma unroll
          for (int rr = 0; rr < 4; ++rr) {
            int n = n0 + nsub * 16 + lg * 4 + rr;
            float x = sacc[nsub][rr];
            if (!full && n > qg) x = -1e30f;
            xs[nsub][rr] = x;
            tmax = fmaxf(tmax, x);
          }
        }
        tmax = fmaxf(tmax, __shfl_xor(tmax, 16));
        tmax = fmaxf(tmax, __shfl_xor(tmax, 32));
        const bool noresc = __all(tmax - m_run <= 8.0f);  // T13 defer-max
        const float m_new = noresc ? m_run : fmaxf(m_run, tmax);
        float psum = 0.0f;
        unsigned int pk_[4][2];
        #pragma unroll
        for (int nsub = 0; nsub < 4; ++nsub) {
          float p0 = __expf(xs[nsub][0] - m_new);
          float p1 = __expf(xs[nsub][1] - m_new);
          float p2 = __expf(xs[nsub][2] - m_new);
          float p3 = __expf(xs[nsub][3] - m_new);
          psum += (p0 + p1) + (p2 + p3);
          pk_[nsub][0] = cvt_pk_bf16(p0, p1);
          pk_[nsub][1] = cvt_pk_bf16(p2, p3);
        }
        psum += __shfl_xor(psum, 16);
        psum += __shfl_xor(psum, 32);
        if (!noresc) {
          const float resc = __expf(m_run - m_new);
          l_run *= resc;
          m_run = m_new;
          float rs[4];
          #pragma unroll
          for (int rr = 0; rr < 4; ++rr) rs[rr] = __shfl(resc, lg * 4 + rr);
          #pragma unroll
          for (int dsub = 0; dsub < 8; ++dsub)
            #pragma unroll
            for (int rr = 0; rr < 4; ++rr) oacc[dsub][rr] *= rs[rr];
        }
        l_run += psum;
        // stage P rows in per-wave LDS (uint2 = ds_write_b64)
        #pragma unroll
        for (int nsub = 0; nsub < 4; ++nsub) {
          uint2 pk2; pk2.x = pk_[nsub][0]; pk2.y = pk_[nsub][1];
          *reinterpret_cast<uint2*>(&pr[nsub * 8 + lg * 2]) = pk2;
        }
      }
      // ---- PV phase: V(t) is oldest; K(t+1) may be in flight ----
      if (t + 1 < nt) {
        asm volatile("s_waitcnt vmcnt(4)" ::: "memory");  // V(t) landed
      } else {
        asm volatile("s_waitcnt vmcnt(0)" ::: "memory");
      }
      __builtin_amdgcn_sched_barrier(0);
      __builtin_amdgcn_s_barrier();   // V(t) visible to all waves
      if (active) {
        __builtin_amdgcn_s_setprio(1);
        #pragma unroll
        for (int nch = 0; nch < 2; ++nch) {
          s16x8 pf = *reinterpret_cast<const s16x8*>(&pr[nch * 16 + lg * 4]);
          #pragma unroll
          for (int dsub = 0; dsub < 8; ++dsub) {
            const int vr = (dsub * 16 + lm) * 64;
            s16x8 vf = ld8(&vbuf[vr + (((nch * 4 + lg) ^ (lm & 7)) * 8)]);
            oacc[dsub] = __builtin_amdgcn_mfma_f32_16x16x32_bf16(pf, vf, oacc[dsub], 0, 0, 0);
          }
        }
        __builtin_amdgcn_s_setprio(0);
      }
      asm volatile("s_waitcnt lgkmcnt(0)" ::: "memory");  // vbuf reads retired
      __builtin_amdgcn_sched_barrier(0);
      __builtin_amdgcn_s_barrier();   // release vbuf
      if (t + 1 < nt) AV(t + 1);      // overlaps next QK
    }
    #undef AK
    #undef AV
    float linv[4];
    #pragma unroll
    for (int rr = 0; rr < 4; ++rr) linv[rr] = 1.0f / __shfl(l_run, lg * 4 + rr);
    #pragma unroll
    for (int dsub = 0; dsub < 8; ++dsub) {
      const int col = h * 128 + dsub * 16 + lm;
      #pragma unroll
      for (int rr = 0; rr < 4; ++rr)
        aout[(size_t)(b * SS + wq0 + lg * 4 + rr) * CC + col] =
            f2bf(oacc[dsub][rr] * linv[rr]);
    }
  }
}

extern "C" void kernel_launch(void* const* d_in, const int* in_sizes, int n_in,
                              void* d_out, int out_size, void* d_ws, size_t ws_size,
                              hipStream_t stream) {
  const float* x      = (const float*)d_in[0];
  const float* w_attn = (const float*)d_in[1];
  const float* b_attn = (const float*)d_in[2];
  const float* w_proj = (const float*)d_in[3];
  const float* b_proj = (const float*)d_in[4];
  float* out = (float*)d_out;

  const size_t M = 4 * (size_t)SS;  // 8192 tokens
  unsigned short* ws = (unsigned short*)d_ws;
  unsigned short* xb   = ws;                        // [8192,768] (dead after GEMM1)
  unsigned short* waT  = xb + M * CC;               // [2304,768]
  unsigned short* wpT  = waT + (size_t)C3 * CC;     // [768,768]
  unsigned short* qkv  = wpT + (size_t)CC * CC;     // [8192,2304]
  unsigned short* aout = qkv + M * C3;              // [8192,768]
  unsigned short* vT   = xb;                        // [24,128,2048] aliases dead xb
  int* ctr = (int*)(aout + M * CC);

  int n4 = (int)(M * CC / 4);
  cast_bf16_kernel<<<(n4 + 255) / 256, 256, 0, stream>>>(x, xb, n4);
  transpose_cast_kernel<<<dim3(C3 / 32, CC / 32), 256, 0, stream>>>(w_attn, waT, CC, C3, CC);
  transpose_cast_kernel<<<dim3(CC / 32, CC / 32), 256, 0, stream>>>(w_proj, wpT, CC, CC, 0);

  gemm_lds_kernel<1><<<dim3(C3 / 128, M / 128), 256, 0, stream>>>(
      xb, waT, b_attn, (void*)qkv, (int)M, C3, CC, CC);

  vtrans_kernel<<<dim3(SS / 64, 24), 256, 0, stream>>>(qkv, vT);

  hipMemsetAsync(ctr, 0, sizeof(int), stream);
  attn_kernel<<<768, 256, 0, stream>>>(qkv, vT, aout, ctr);

  gemm_lds_kernel<0><<<dim3(CC / 128, M / 128), 256, 0, stream>>>(
      aout, wpT, b_proj, (void*)out, (int)M, CC, CC, 0);
}

// Round 13
// 159.171 us; speedup vs baseline: 1.0895x; 1.0675x over previous
//
#include <hip/hip_runtime.h>
#include <hip/hip_bf16.h>
#include <stdint.h>

// CausalMultiHeadAttention: B=4 S=2048 C=768 H=6 D=128
// cast(x,wT,Q-prescale) -> GEMM1(depth-2 counted-vmcnt, 3-buf) -> V-transpose ->
// flash-attn(r10 structure: 4-wave blocks, dbuf K+V, dynamic LPT queue) -> GEMM2
#define SS 2048
#define CC 768
#define C3 2304
#define NITEMS (32 * 24)  // 64-row q-tiles x (b,h)
#define QSC 0.08838834764831845f  // 1/sqrt(128), folded into Q weights+bias

typedef float f32x4 __attribute__((ext_vector_type(4)));
typedef short s16x8 __attribute__((ext_vector_type(8)));

__device__ __forceinline__ unsigned short f2bf(float f) {
  union { float f; unsigned int u; } v; v.f = f;
  unsigned int r = (v.u + 0x7FFFu + ((v.u >> 16) & 1u)) >> 16;
  return (unsigned short)r;
}

__device__ __forceinline__ s16x8 ld8(const unsigned short* p) {
  return *reinterpret_cast<const s16x8*>(p);
}

__device__ __forceinline__ unsigned int cvt_pk_bf16(float lo, float hi) {
  unsigned int r;
  asm("v_cvt_pk_bf16_f32 %0, %1, %2" : "=v"(r) : "v"(lo), "v"(hi));
  return r;
}

// async global->LDS, 16B/lane. LDS dest = wave-uniform base + lane*16 (linear);
// per-lane global src carries the swizzle (rule #21: linear dest + inv-swz src).
__device__ __forceinline__ void gload_lds16(const unsigned short* g, unsigned short* l) {
  __builtin_amdgcn_global_load_lds(
      (const __attribute__((address_space(1))) void*)g,
      (__attribute__((address_space(3))) void*)l, 16, 0, 0);
}

__global__ __launch_bounds__(256) void cast_bf16_kernel(
    const float* __restrict__ src, unsigned short* __restrict__ dst, int n4) {
  int i = blockIdx.x * 256 + threadIdx.x;
  if (i < n4) {
    float4 v = reinterpret_cast<const float4*>(src)[i];
    ushort4 o;
    o.x = f2bf(v.x); o.y = f2bf(v.y); o.z = f2bf(v.z); o.w = f2bf(v.w);
    reinterpret_cast<ushort4*>(dst)[i] = o;
  }
}

// src [R][C] f32 -> dst [C][R] bf16; dst rows < nsc get scaled by QSC (Q fold)
__global__ __launch_bounds__(256) void transpose_cast_kernel(
    const float* __restrict__ src, unsigned short* __restrict__ dst, int R, int C,
    int nsc) {
  __shared__ float tile[32][33];
  int c0 = blockIdx.x * 32, r0 = blockIdx.y * 32;
  int tx = threadIdx.x & 31, ty = threadIdx.x >> 5;
  #pragma unroll
  for (int i = 0; i < 32; i += 8)
    tile[ty + i][tx] = src[(size_t)(r0 + ty + i) * C + c0 + tx];
  __syncthreads();
  #pragma unroll
  for (int i = 0; i < 32; i += 8) {
    int oc = c0 + ty + i;
    float v = tile[tx][ty + i];
    if (oc < nsc) v *= QSC;
    dst[(size_t)oc * R + r0 + tx] = f2bf(v);
  }
}

// V region of qkv [token][C3] -> vT [bh][d=128][n=S], 64x128 tiles via swizzled LDS
__global__ __launch_bounds__(256) void vtrans_kernel(
    const unsigned short* __restrict__ qkv, unsigned short* __restrict__ vT) {
  __shared__ unsigned short t[64 * 128];
  const int tid = threadIdx.x;
  const int n0 = blockIdx.x * 64;
  const int bh = blockIdx.y;
  const int b = bh / 6, h = bh % 6;
  #pragma unroll
  for (int it = 0; it < 4; ++it) {
    int c = it * 256 + tid;
    int n = c >> 4, slot = c & 15;
    s16x8 v = ld8(qkv + (size_t)(b * SS + n0 + n) * C3 + 2 * CC + h * 128 + slot * 8);
    int ss = slot ^ ((n >> 3) & 7);
    *reinterpret_cast<s16x8*>(&t[n * 128 + ss * 8]) = v;
  }
  __syncthreads();
  #pragma unroll
  for (int it = 0; it < 4; ++it) {
    int c = it * 256 + tid;
    int d = c >> 3, n8 = (c & 7) * 8;
    s16x8 o;
    #pragma unroll
    for (int j = 0; j < 8; ++j) {
      int n = n8 + j;
      int sl = (d >> 3) ^ ((n >> 3) & 7);
      o[j] = (short)t[n * 128 + sl * 8 + (d & 7)];
    }
    *reinterpret_cast<s16x8*>(&vT[((size_t)bh * 128 + d) * SS + n0 + n8]) = o;
  }
}

// C[m][n] = sum_k A[m][k]*Bt[n][k] + bias[n]. 128x128 tile, BK=32, 3 LDS bufs.
// Depth-2 counted-vmcnt pipeline, per K-step:
//   stage(t+2) -> wait vmcnt(8/4/0 per tail) -> bar -> compute(t)
//   -> lgkmcnt(0) -> sched -> bar
// WAR proof: stage(t+2) writes buf[(t+2)%3] = buf[(t-1)%3]; its last reader
// compute(t-1) retired ds_reads before end-barrier of t-1; stage(t+2) is
// issued after that barrier. No dummy stages: explicit tail waits (r8 fix).
template <int OUT_BF16>
__global__ __launch_bounds__(256) void gemm_lds_kernel(
    const unsigned short* __restrict__ A, const unsigned short* __restrict__ Bt,
    const float* __restrict__ bias, void* __restrict__ out, int M, int N, int K,
    int nsc) {
  __shared__ unsigned short lA[3][128 * 32];
  __shared__ unsigned short lB[3][128 * 32];
  const int tid = threadIdx.x, lane = tid & 63, w = tid >> 6;
  // XCD-bijective swizzle (nwg % 8 == 0 for all our grids)
  const int nbx = gridDim.x;
  int bid = blockIdx.y * nbx + blockIdx.x;
  const int cpx = (nbx * gridDim.y) >> 3;
  bid = (bid & 7) * cpx + (bid >> 3);
  const int m0 = (bid / nbx) * 128, n0 = (bid % nbx) * 128;
  const int lm = lane & 15, lg = lane >> 4;
  const int wm = (w >> 1) * 64, wn = (w & 1) * 64;
  const int sr = lane >> 2;                            // row-in-chunk 0..15
  const int ssl = ((lane & 3) ^ ((sr >> 1) & 3)) * 8;  // inv-swizzled k-slot
  int aOff[4], bOff[4];
  #pragma unroll
  for (int i = 0; i < 4; ++i) {
    int ra = wm + i * 16 + lm, rb = wn + i * 16 + lm;
    aOff[i] = ra * 32 + ((lg ^ ((ra >> 1) & 3)) * 8);
    bOff[i] = rb * 32 + ((lg ^ ((rb >> 1) & 3)) * 8);
  }
  f32x4 acc[4][4] = {};
  const int nt = K / 32;
  #define GSTAGE(tt, bb)                                                      \
    {                                                                         \
      const int k0_ = (tt) * 32;                                              \
      _Pragma("unroll")                                                       \
      for (int i_ = 0; i_ < 2; ++i_) {                                        \
        int c_ = w * 2 + i_;                                                  \
        int row_ = c_ * 16 + sr;                                              \
        gload_lds16(A + (size_t)(m0 + row_) * K + k0_ + ssl, &lA[bb][c_ * 512]); \
        gload_lds16(Bt + (size_t)(n0 + row_) * K + k0_ + ssl, &lB[bb][c_ * 512]); \
      }                                                                       \
    }
  GSTAGE(0, 0);
  if (nt > 1) GSTAGE(1, 1);
  #pragma unroll 1
  for (int t = 0; t < nt; ++t) {
    if (t + 2 < nt) {
      GSTAGE(t + 2, (t + 2) % 3);                       // depth-2 prefetch
      asm volatile("s_waitcnt vmcnt(8)" ::: "memory");  // tile t landed
    } else if (t + 1 < nt) {
      asm volatile("s_waitcnt vmcnt(4)" ::: "memory");  // [t+1] in flight only
    } else {
      asm volatile("s_waitcnt vmcnt(0)" ::: "memory");
    }
    __builtin_amdgcn_sched_barrier(0);
    __builtin_amdgcn_s_barrier();   // all waves' chunks of tile t visible
    const int cu = t % 3;
    s16x8 af[4], bf[4];
    #pragma unroll
    for (int i = 0; i < 4; ++i) af[i] = ld8(&lA[cu][aOff[i]]);
    #pragma unroll
    for (int i = 0; i < 4; ++i) bf[i] = ld8(&lB[cu][bOff[i]]);
    __builtin_amdgcn_s_setprio(1);
    #pragma unroll
    for (int mi = 0; mi < 4; ++mi)
      #pragma unroll
      for (int ni = 0; ni < 4; ++ni)
        acc[mi][ni] = __builtin_amdgcn_mfma_f32_16x16x32_bf16(af[mi], bf[ni], acc[mi][ni], 0, 0, 0);
    __builtin_amdgcn_s_setprio(0);
    asm volatile("s_waitcnt lgkmcnt(0)" ::: "memory");  // LDS reads retired
    __builtin_amdgcn_sched_barrier(0);                  // rule #18 fence
    __builtin_amdgcn_s_barrier();   // release buf t%3 for stage(t+3)
  }
  #pragma unroll
  for (int mi = 0; mi < 4; ++mi) {
    #pragma unroll
    for (int ni = 0; ni < 4; ++ni) {
      const int row = m0 + wm + mi * 16 + lg * 4;
      const int col = n0 + wn + ni * 16 + lm;
      float bs = bias[col];
      if (col < nsc) bs *= QSC;
      #pragma unroll
      for (int r = 0; r < 4; ++r) {
        float v = acc[mi][ni][r] + bs;
        if (OUT_BF16)
          ((unsigned short*)out)[(size_t)(row + r) * N + col] = f2bf(v);
        else
          ((float*)out)[(size_t)(row + r) * N + col] = v;
      }
    }
  }
  #undef GSTAGE
}

// Flash attention, causal — r10-exact structure (best measured: 86us).
// Block-level dynamic LPT queue, item = (bh, 64-row q-tile). 4 waves/block.
// K and V double-buffered in LDS; per tile: stage(t+1) -> vmcnt(8|0) -> bar ->
// QK -> softmax -> PV -> lgkm fence -> bar. Q pre-scaled by 1/sqrt(D) (folded).
__global__ __launch_bounds__(256) void attn_kernel(
    const unsigned short* __restrict__ qkv,
    const unsigned short* __restrict__ vT,
    unsigned short* __restrict__ aout,
    int* __restrict__ ctr) {
  const int tid = threadIdx.x, lane = tid & 63, w = tid >> 6;
  const int lm = lane & 15, lg = lane >> 4;
  __shared__ unsigned short kbuf[2][64 * 128];  // [kv-row][128], slot-swizzled
  __shared__ unsigned short vbuf[2][128 * 64];  // [d][64], slot-swizzled
  __shared__ unsigned int pb[4][16 * 44];       // per-wave P rows, u32 stride 44
  __shared__ int s_item;
  unsigned int* pr = &pb[w][lm * 44];
  const int klg4 = lane >> 4, ks16 = lane & 15;  // K staging: row-in-4, slot
  const int vlg8 = lane >> 3, vs8 = lane & 7;    // V staging: d-in-8, slot
  for (;;) {
    __syncthreads();
    if (tid == 0) s_item = atomicAdd(ctr, 1);
    __syncthreads();
    const int item = s_item;
    if (item >= NITEMS) return;
    const int qt = 31 - (item / 24);  // expensive q-tiles first (LPT)
    const int bh = item % 24;
    const int b = bh / 6, h = bh % 6;
    const int q0 = qt * 64, wq0 = q0 + w * 16;
    const unsigned short* base = qkv + (size_t)b * SS * C3;
    const unsigned short* kg = base + CC + h * 128;
    const unsigned short* vg = vT + (size_t)bh * 128 * SS;
    s16x8 qf[4];
    {
      const unsigned short* qp = base + (size_t)(wq0 + lm) * C3 + h * 128 + lg * 8;
      #pragma unroll
      for (int ks = 0; ks < 4; ++ks) qf[ks] = ld8(qp + ks * 32);
    }
    #define ASTAGE(tt, bb)                                                    \
      {                                                                       \
        const int n1_ = (tt) * 64;                                            \
        _Pragma("unroll")                                                     \
        for (int i_ = 0; i_ < 4; ++i_) {                                      \
          int c_ = w * 4 + i_;                                                \
          int r_ = c_ * 4 + klg4;                                             \
          gload_lds16(kg + (size_t)(n1_ + r_) * C3 + ((ks16 ^ (r_ & 7)) * 8), \
                      &kbuf[bb][c_ * 512]);                                   \
        }                                                                     \
        _Pragma("unroll")                                                     \
        for (int i_ = 0; i_ < 4; ++i_) {                                      \
          int c_ = w * 4 + i_;                                                \
          int d_ = c_ * 8 + vlg8;                                             \
          gload_lds16(vg + (size_t)d_ * SS + n1_ + ((vs8 ^ (d_ & 7)) * 8),    \
                      &vbuf[bb][c_ * 512]);                                   \
        }                                                                     \
      }
    f32x4 oacc[8] = {};
    float m_run = -1e30f, l_run = 0.0f;
    const int nt = qt + 1;  // 64-wide kv tiles
    ASTAGE(0, 0);
    #pragma unroll 1
    for (int t = 0; t < nt; ++t) {
      if (t + 1 < nt) {
        ASTAGE(t + 1, (t + 1) & 1);                       // 8 more in flight
        asm volatile("s_waitcnt vmcnt(8)" ::: "memory");  // tile t landed
      } else {
        asm volatile("s_waitcnt vmcnt(0)" ::: "memory");
      }
      __builtin_amdgcn_sched_barrier(0);
      __builtin_amdgcn_s_barrier();   // all waves' chunks of tile t visible
      const int n0 = t * 64;
      const int cu = t & 1;
      const unsigned short* kb = kbuf[cu];
      const unsigned short* vb = vbuf[cu];
      // QK^T swapped: sacc[nsub] = S^T[n][q], n = n0+nsub*16+lg*4+r, q = lm
      f32x4 sacc[4] = {};
      __builtin_amdgcn_s_setprio(1);
      #pragma unroll
      for (int nsub = 0; nsub < 4; ++nsub) {
        const int kr = (nsub * 16 + lm) * 128;
        #pragma unroll
        for (int ks = 0; ks < 4; ++ks) {
          s16x8 kf = ld8(&kb[kr + (((ks * 4 + lg) ^ (lm & 7)) * 8)]);
          sacc[nsub] = __builtin_amdgcn_mfma_f32_16x16x32_bf16(kf, qf[ks], sacc[nsub], 0, 0, 0);
        }
      }
      __builtin_amdgcn_s_setprio(0);
      const int qg = wq0 + lm;
      const bool full = (n0 + 63 <= wq0);
      float xs[4][4];
      float tmax = -1e30f;
      #pragma unroll
      for (int nsub = 0; nsub < 4; ++nsub) {
        #pragma unroll
        for (int r = 0; r < 4; ++r) {
          int n = n0 + nsub * 16 + lg * 4 + r;
          float x = sacc[nsub][r];   // Q pre-scaled: no multiply here
          if (!full && n > qg) x = -1e30f;
          xs[nsub][r] = x;
          tmax = fmaxf(tmax, x);
        }
      }
      tmax = fmaxf(tmax, __shfl_xor(tmax, 16));
      tmax = fmaxf(tmax, __shfl_xor(tmax, 32));
      // T13 defer-max: skip rescale when max growth <= 8 (P bounded by e^8)
      const bool noresc = __all(tmax - m_run <= 8.0f);
      const float m_new = noresc ? m_run : fmaxf(m_run, tmax);
      float psum = 0.0f;
      unsigned int pk_[4][2];
      #pragma unroll
      for (int nsub = 0; nsub < 4; ++nsub) {
        float p0 = __expf(xs[nsub][0] - m_new);
        float p1 = __expf(xs[nsub][1] - m_new);
        float p2 = __expf(xs[nsub][2] - m_new);
        float p3 = __expf(xs[nsub][3] - m_new);
        psum += (p0 + p1) + (p2 + p3);
        pk_[nsub][0] = cvt_pk_bf16(p0, p1);
        pk_[nsub][1] = cvt_pk_bf16(p2, p3);
      }
      psum += __shfl_xor(psum, 16);
      psum += __shfl_xor(psum, 32);
      if (!noresc) {
        const float resc = __expf(m_run - m_new);
        l_run *= resc;
        m_run = m_new;
        float rs[4];
        #pragma unroll
        for (int r = 0; r < 4; ++r) rs[r] = __shfl(resc, lg * 4 + r);
        #pragma unroll
        for (int dsub = 0; dsub < 8; ++dsub)
          #pragma unroll
          for (int r = 0; r < 4; ++r) oacc[dsub][r] *= rs[r];
      }
      l_run += psum;
      // stage P rows in per-wave LDS (uint2 = ds_write_b64)
      #pragma unroll
      for (int nsub = 0; nsub < 4; ++nsub) {
        uint2 pk2; pk2.x = pk_[nsub][0]; pk2.y = pk_[nsub][1];
        *reinterpret_cast<uint2*>(&pr[nsub * 8 + lg * 2]) = pk2;
      }
      // PV: A = P[q=lm][n-chunk], B = V^T frags from swizzled LDS
      __builtin_amdgcn_s_setprio(1);
      #pragma unroll
      for (int nch = 0; nch < 2; ++nch) {
        s16x8 pf = *reinterpret_cast<const s16x8*>(&pr[nch * 16 + lg * 4]);
        #pragma unroll
        for (int dsub = 0; dsub < 8; ++dsub) {
          const int vr = (dsub * 16 + lm) * 64;
          s16x8 vf = ld8(&vb[vr + (((nch * 4 + lg) ^ (lm & 7)) * 8)]);
          oacc[dsub] = __builtin_amdgcn_mfma_f32_16x16x32_bf16(pf, vf, oacc[dsub], 0, 0, 0);
        }
      }
      __builtin_amdgcn_s_setprio(0);
      asm volatile("s_waitcnt lgkmcnt(0)" ::: "memory");  // LDS reads retired
      __builtin_amdgcn_sched_barrier(0);                  // rule #18 fence
      __builtin_amdgcn_s_barrier();   // release buf t&1 for stage(t+2)
    }
    #undef ASTAGE
    float linv[4];
    #pragma unroll
    for (int r = 0; r < 4; ++r) linv[r] = 1.0f / __shfl(l_run, lg * 4 + r);
    #pragma unroll
    for (int dsub = 0; dsub < 8; ++dsub) {
      const int col = h * 128 + dsub * 16 + lm;
      #pragma unroll
      for (int r = 0; r < 4; ++r)
        aout[(size_t)(b * SS + wq0 + lg * 4 + r) * CC + col] =
            f2bf(oacc[dsub][r] * linv[r]);
    }
  }
}

extern "C" void kernel_launch(void* const* d_in, const int* in_sizes, int n_in,
                              void* d_out, int out_size, void* d_ws, size_t ws_size,
                              hipStream_t stream) {
  const float* x      = (const float*)d_in[0];
  const float* w_attn = (const float*)d_in[1];
  const float* b_attn = (const float*)d_in[2];
  const float* w_proj = (const float*)d_in[3];
  const float* b_proj = (const float*)d_in[4];
  float* out = (float*)d_out;

  const size_t M = 4 * (size_t)SS;  // 8192 tokens
  unsigned short* ws = (unsigned short*)d_ws;
  unsigned short* xb   = ws;                        // [8192,768] (dead after GEMM1)
  unsigned short* waT  = xb + M * CC;               // [2304,768]
  unsigned short* wpT  = waT + (size_t)C3 * CC;     // [768,768]
  unsigned short* qkv  = wpT + (size_t)CC * CC;     // [8192,2304]
  unsigned short* aout = qkv + M * C3;              // [8192,768]
  unsigned short* vT   = xb;                        // [24,128,2048] aliases dead xb
  int* ctr = (int*)(aout + M * CC);

  int n4 = (int)(M * CC / 4);
  cast_bf16_kernel<<<(n4 + 255) / 256, 256, 0, stream>>>(x, xb, n4);
  transpose_cast_kernel<<<dim3(C3 / 32, CC / 32), 256, 0, stream>>>(w_attn, waT, CC, C3, CC);
  transpose_cast_kernel<<<dim3(CC / 32, CC / 32), 256, 0, stream>>>(w_proj, wpT, CC, CC, 0);

  gemm_lds_kernel<1><<<dim3(C3 / 128, M / 128), 256, 0, stream>>>(
      xb, waT, b_attn, (void*)qkv, (int)M, C3, CC, CC);

  vtrans_kernel<<<dim3(SS / 64, 24), 256, 0, stream>>>(qkv, vT);

  hipMemsetAsync(ctr, 0, sizeof(int), stream);
  attn_kernel<<<512, 256, 0, stream>>>(qkv, vT, aout, ctr);

  gemm_lds_kernel<0><<<dim3(CC / 128, M / 128), 256, 0, stream>>>(
      aout, wpT, b_proj, (void*)out, (int)M, CC, CC, 0);
}